// Round 10
// baseline (1549.544 us; speedup 1.0000x reference)
//
#include <hip/hip_runtime.h>
#include <hip/hip_bf16.h>
#include <cmath>

#define NN 100000
#define NE 1600000
#define FIN 512
#define HD 128
#define NC 40
#define NL 8
#define NBK 196                      // ceil(NN / 512) buckets of 512 dsts
#define P1B 256                      // partition blocks
#define CHUNK ((NE + P1B - 1) / P1B) // edges per partition block
#define ATILE 512                    // dsts per agg block
#define NTILE ((NN + ATILE - 1) / ATILE)

typedef __attribute__((ext_vector_type(8))) short bh8;
typedef __attribute__((ext_vector_type(4))) float f4;
typedef __attribute__((ext_vector_type(4))) unsigned int u4;
typedef __attribute__((ext_vector_type(2))) unsigned int u2;

__device__ __forceinline__ float bflo(unsigned p){ return __uint_as_float(p << 16); }
__device__ __forceinline__ float bfhi(unsigned p){ return __uint_as_float(p & 0xffff0000u); }
__device__ __forceinline__ unsigned short f2bf(float f){
  unsigned u = __float_as_uint(f);
  u += 0x7fffu + ((u >> 16) & 1u);
  return (unsigned short)(u >> 16);
}
__device__ __forceinline__ unsigned pack2(float a, float b){
  return (unsigned)f2bf(a) | ((unsigned)f2bf(b) << 16);
}

// ---------------- CSR build: radix partition by dst ----------------
__global__ __launch_bounds__(256) void k_hist(const int* __restrict__ dst,
                                              int* __restrict__ bcnt){
  __shared__ int h[256];
  int t = threadIdx.x;
  h[t] = 0;
  __syncthreads();
  int lo = blockIdx.x * CHUNK;
  int hi = lo + CHUNK < NE ? lo + CHUNK : NE;
  for (int i = lo + t; i < hi; i += 256)
    atomicAdd(&h[dst[i] >> 9], 1);
  __syncthreads();
  if (h[t]) atomicAdd(&bcnt[t], h[t]);
}

__global__ void k_bscan(const int* __restrict__ bcnt, int* __restrict__ gbase,
                        int* __restrict__ gcur, int* __restrict__ offs){
  int t = threadIdx.x;   // 64 threads
  int carry = 0;
  for (int base = 0; base < 256; base += 64){
    int v = bcnt[base + t];
    int orig = v;
    #pragma unroll
    for (int off = 1; off < 64; off <<= 1){
      int u = __shfl_up(v, off);
      if (t >= off) v += u;
    }
    int excl = carry + v - orig;
    gbase[base + t] = excl;
    gcur[base + t] = excl;
    carry += __shfl(v, 63);
  }
  if (t == 0){ gbase[256] = carry; offs[NN] = NE; }
}

__global__ __launch_bounds__(256) void k_part(const int* __restrict__ src,
                                              const int* __restrict__ dst,
                                              const float* __restrict__ w,
                                              int* __restrict__ gcur,
                                              u2* __restrict__ tmp){
  __shared__ int h[256];
  __shared__ int base[256];
  int t = threadIdx.x;
  h[t] = 0;
  __syncthreads();
  int lo = blockIdx.x * CHUNK;
  int hi = lo + CHUNK < NE ? lo + CHUNK : NE;
  for (int i = lo + t; i < hi; i += 256)
    atomicAdd(&h[dst[i] >> 9], 1);
  __syncthreads();
  int cnt = h[t];
  if (cnt) base[t] = atomicAdd(&gcur[t], cnt);
  h[t] = 0;
  __syncthreads();
  for (int i = lo + t; i < hi; i += 256){
    int d = dst[i];
    int bk = d >> 9;
    int r = atomicAdd(&h[bk], 1);
    u2 v = { (unsigned)src[i] | ((unsigned)(d & 511) << 17), __float_as_uint(w[i]) };
    tmp[base[bk] + r] = v;
  }
}

__global__ __launch_bounds__(256) void k_place(const u2* __restrict__ tmp,
                                               const int* __restrict__ gbase,
                                               int* __restrict__ offs,
                                               u2* __restrict__ epk){
  __shared__ int h[512];
  __shared__ int lofs[512];
  int b = blockIdx.x;
  int t = threadIdx.x;
  int e0 = gbase[b], e1 = gbase[b + 1];
  h[t] = 0; h[t + 256] = 0;
  __syncthreads();
  for (int i = e0 + t; i < e1; i += 256)
    atomicAdd(&h[tmp[i].x >> 17], 1);
  __syncthreads();
  if (t < 64){
    int carry = 0;
    for (int base = 0; base < 512; base += 64){
      int v = h[base + t];
      int orig = v;
      #pragma unroll
      for (int off = 1; off < 64; off <<= 1){
        int u = __shfl_up(v, off);
        if (t >= off) v += u;
      }
      lofs[base + t] = carry + v - orig;
      carry += __shfl(v, 63);
    }
  }
  __syncthreads();
  int d = b * 512 + t;
  if (d < NN) offs[d] = e0 + lofs[t];
  int d2 = b * 512 + 256 + t;
  if (d2 < NN) offs[d2] = e0 + lofs[256 + t];
  h[t] = 0; h[t + 256] = 0;
  __syncthreads();
  for (int i = e0 + t; i < e1; i += 256){
    u2 v = tmp[i];
    int d9 = v.x >> 17;
    int r = atomicAdd(&h[d9], 1);
    u2 o = { v.x & 0x1FFFFu, v.y };
    epk[e0 + lofs[d9] + r] = o;
  }
}

// ---------------- all weight transposes in one kernel ----------------
__global__ void k_twt_all(const float* __restrict__ W0, const float* __restrict__ cW,
                          const float* __restrict__ W1, unsigned short* __restrict__ out){
  const int n0 = FIN * HD;
  const int n1 = NL * HD * HD;
  const int total = n0 + n1 + 48 * HD;
  for (int i = blockIdx.x * blockDim.x + threadIdx.x; i < total; i += gridDim.x * blockDim.x){
    float v;
    if (i < n0){
      int c = i / FIN, k = i % FIN;
      v = W0[(size_t)k * HD + c];
    } else if (i < n0 + n1){
      int j = i - n0;
      int l = j / (HD * HD), r = j % (HD * HD);
      int c = r / HD, k = r % HD;
      v = cW[(size_t)l * HD * HD + k * HD + c];
    } else {
      int j = i - n0 - n1;
      int c = j / HD, k = j % HD;
      v = (c < NC) ? W1[(size_t)k * NC + c] : 0.f;
    }
    out[i] = f2bf(v);
  }
}

// ---------------- GEMM0: h0 = relu(x @ W0 + b0), write SLICED bf16 to two buffers ----------------
// sliced layout: region s (s=0..7) holds features [16s,16s+16) as NN rows x 8 u32
__global__ __launch_bounds__(256) void k_gemm0(const float* __restrict__ X,
                                               const unsigned short* __restrict__ Wt,
                                               const float* __restrict__ b0,
                                               unsigned* __restrict__ Ha,
                                               unsigned* __restrict__ Hb, int n){
  __shared__ __attribute__((aligned(16))) char lds[33792];
  char* ldsA = lds;           // 64 rows x 64 k bf16 (row stride 128 B)
  char* ldsW = lds + 8192;    // 128 c x 64 k bf16
  float* ldsO = (float*)lds;  // 64 x 132 f32 (reuse)
  int t = threadIdx.x;
  int w = t >> 6, lane = t & 63;
  int rowBase = blockIdx.x * 64;
  f4 acc[8];
  #pragma unroll
  for (int i = 0; i < 8; i++) acc[i] = (f4)0.f;

  for (int kk = 0; kk < 8; kk++){
    #pragma unroll
    for (int iter = 0; iter < 2; iter++){
      int r = t / 8 + iter * 32;
      int kc = (t % 8) * 8;
      int grow = rowBase + r;
      float4 f0 = {0,0,0,0}, f1 = {0,0,0,0};
      if (grow < n){
        const float4* p = (const float4*)(X + (size_t)grow * FIN + kk * 64 + kc);
        f0 = p[0]; f1 = p[1];
      }
      u4 pv = { pack2(f0.x, f0.y), pack2(f0.z, f0.w), pack2(f1.x, f1.y), pack2(f1.z, f1.w) };
      *(u4*)(ldsA + r * 128 + ((kc * 2) ^ ((r & 7) << 4))) = pv;
    }
    #pragma unroll
    for (int iter = 0; iter < 4; iter++){
      int c = t / 8 + iter * 32;
      int kc = (t % 8) * 8;
      bh8 v = *(const bh8*)(Wt + (size_t)c * FIN + kk * 64 + kc);
      *(bh8*)(ldsW + c * 128 + ((kc * 2) ^ ((c & 7) << 4))) = v;
    }
    __syncthreads();
    int rowf = (w << 4) + (lane & 15);
    #pragma unroll
    for (int ks = 0; ks < 2; ks++){
      bh8 fa = *(const bh8*)(ldsA + rowf * 128 + ((ks * 64 + (lane >> 4) * 16) ^ ((rowf & 7) << 4)));
      #pragma unroll
      for (int ct = 0; ct < 8; ct++){
        int colf = (ct << 4) + (lane & 15);
        bh8 fb = *(const bh8*)(ldsW + colf * 128 + ((ks * 64 + (lane >> 4) * 16) ^ ((colf & 7) << 4)));
        acc[ct] = __builtin_amdgcn_mfma_f32_16x16x32_bf16(fa, fb, acc[ct], 0, 0, 0);
      }
    }
    __syncthreads();
  }
  #pragma unroll
  for (int ct = 0; ct < 8; ct++){
    int colf = (ct << 4) + (lane & 15);
    float bb = b0[colf];
    #pragma unroll
    for (int i = 0; i < 4; i++){
      int r = (w << 4) + ((lane >> 4) << 2) + i;
      float v = acc[ct][i] + bb;
      ldsO[r * 132 + colf] = v > 0.f ? v : 0.f;
    }
  }
  __syncthreads();
  int r2 = t >> 2, p = t & 3;
  #pragma unroll
  for (int s = 0; s < 8; s++){
    int grow = rowBase + r2;
    if (grow < n){
      float* pp = &ldsO[r2 * 132 + s * 16 + p * 4];
      u2 pv = { pack2(pp[0], pp[1]), pack2(pp[2], pp[3]) };
      *(u2*)(Ha + (size_t)s * NN * 8 + (size_t)grow * 8 + p * 2) = pv;
      *(u2*)(Hb + (size_t)s * NN * 8 + (size_t)grow * 8 + p * 2) = pv;
    }
  }
}

// ---------------- sliced aggregation: T_s[d] = 0.9 * sum w_e * H_s[src_e] + 0.1 * X0_s[d] ----------------
// slice = blockIdx % 8 -> lands on one XCD (de-facto round-robin), H-slice is L2-resident (3.2 MB)
__global__ __launch_bounds__(256) void k_agg(const unsigned* __restrict__ Hs,
                                             const unsigned* __restrict__ X0s,
                                             const int* __restrict__ offs,
                                             const u2* __restrict__ epk,
                                             unsigned* __restrict__ Ts, int n){
  int b = blockIdx.x;
  int s = b & 7;
  int tile = b >> 3;
  int t = threadIdx.x;
  int g = t >> 3;         // group 0..31 (8 lanes each)
  int j = t & 7;          // feature-pair index within slice
  const unsigned* Hb = Hs + (size_t)s * NN * 8;
  const unsigned* Xb = X0s + (size_t)s * NN * 8;
  unsigned* Tb = Ts + (size_t)s * NN * 8;
  int d0 = tile * ATILE + g * 16;
  #pragma unroll 1
  for (int dd = 0; dd < 16; dd++){
    int d = d0 + dd;
    if (d >= n) break;
    int e0 = offs[d], e1 = offs[d + 1];
    float ax = 0.f, ay = 0.f;
    int e = e0;
    for (; e + 3 < e1; e += 4){
      u2 p0 = epk[e], p1 = epk[e + 1], p2 = epk[e + 2], p3 = epk[e + 3];
      unsigned h0 = Hb[(size_t)p0.x * 8 + j];
      unsigned h1 = Hb[(size_t)p1.x * 8 + j];
      unsigned h2 = Hb[(size_t)p2.x * 8 + j];
      unsigned h3 = Hb[(size_t)p3.x * 8 + j];
      float w0 = __uint_as_float(p0.y), w1 = __uint_as_float(p1.y);
      float w2 = __uint_as_float(p2.y), w3 = __uint_as_float(p3.y);
      ax += w0*bflo(h0) + w1*bflo(h1) + w2*bflo(h2) + w3*bflo(h3);
      ay += w0*bfhi(h0) + w1*bfhi(h1) + w2*bfhi(h2) + w3*bfhi(h3);
    }
    for (; e < e1; e++){
      u2 pe = epk[e];
      unsigned h = Hb[(size_t)pe.x * 8 + j];
      float wf = __uint_as_float(pe.y);
      ax += wf * bflo(h); ay += wf * bfhi(h);
    }
    unsigned xv = Xb[(size_t)d * 8 + j];
    float vx = 0.9f * ax + 0.1f * bflo(xv);
    float vy = 0.9f * ay + 0.1f * bfhi(xv);
    Tb[(size_t)d * 8 + j] = pack2(vx, vy);
  }
}

// ---------------- layer GEMM: H = relu((1-beta)*T + beta*(T @ W)), sliced I/O ----------------
__global__ __launch_bounds__(256) void k_gemmL(const unsigned* __restrict__ Ts,
                                               const unsigned short* __restrict__ Wt,
                                               float beta,
                                               unsigned* __restrict__ Hs, int n){
  __shared__ __attribute__((aligned(16))) char ldsA[16384];  // 64 x 128 bf16, swizzled
  int t = threadIdx.x;
  int w = t >> 6, lane = t & 63;
  int q = lane >> 4, l16 = lane & 15;
  int rowBase = blockIdx.x * 64;
  int r2 = t >> 2, p = t & 3;

  // load A tile from sliced T (thread t loads row t>>2, which belongs to wave t>>6's rows)
  #pragma unroll
  for (int s = 0; s < 8; s++){
    int grow = rowBase + r2;
    u2 v = { 0u, 0u };
    if (grow < n) v = *(const u2*)(Ts + (size_t)s * NN * 8 + (size_t)grow * 8 + p * 2);
    *(u2*)(ldsA + r2 * 256 + ((s * 32 + p * 8) ^ ((r2 & 7) << 4))) = v;
  }
  // no barrier: each wave wrote exactly the rows it reads below

  f4 acc[8];
  #pragma unroll
  for (int i = 0; i < 8; i++) acc[i] = (f4)0.f;
  int rowf = (w << 4) + l16;
  #pragma unroll
  for (int ks = 0; ks < 4; ks++){
    bh8 fa = *(const bh8*)(ldsA + rowf * 256 + ((ks * 64 + q * 16) ^ ((rowf & 7) << 4)));
    #pragma unroll
    for (int ct = 0; ct < 8; ct++){
      int colf = (ct << 4) + l16;
      bh8 fb = *(const bh8*)(Wt + (size_t)colf * HD + ks * 32 + q * 8);
      acc[ct] = __builtin_amdgcn_mfma_f32_16x16x32_bf16(fa, fb, acc[ct], 0, 0, 0);
    }
  }

  // epilogue: identity-mix from own ldsA rows, relu, write back bf16 (wave-own rows)
  #pragma unroll
  for (int ct = 0; ct < 8; ct++){
    int colf = (ct << 4) + l16;
    #pragma unroll
    for (int i = 0; i < 4; i++){
      int r = (w << 4) + (q << 2) + i;
      char* addr = ldsA + r * 256 + ((colf * 2) ^ ((r & 7) << 4));
      unsigned short tv = *(const unsigned short*)addr;
      float tf = __uint_as_float(((unsigned)tv) << 16);
      float v = (1.f - beta) * tf + beta * acc[ct][i];
      *(unsigned short*)addr = f2bf(v > 0.f ? v : 0.f);
    }
  }
  __syncthreads();

  // sliced store
  #pragma unroll
  for (int s = 0; s < 8; s++){
    int grow = rowBase + r2;
    if (grow < n){
      u2 v = *(const u2*)(ldsA + r2 * 256 + ((s * 32 + p * 8) ^ ((r2 & 7) << 4)));
      *(u2*)(Hs + (size_t)s * NN * 8 + (size_t)grow * 8 + p * 2) = v;
    }
  }
}

// ---------------- head + log_softmax: MFMA 64x48 tile, in-register softmax ----------------
__global__ __launch_bounds__(256) void k_final(const unsigned* __restrict__ Hs,
                                               const unsigned short* __restrict__ W1t, // [48][128]
                                               const float* __restrict__ b1,
                                               float* __restrict__ out, int n){
  __shared__ __attribute__((aligned(16))) char lds[16384 + 12288];
  char* ldsA = lds;            // 64 x 128 bf16, swizzled
  char* ldsW = lds + 16384;    // 48 x 128 bf16
  int t = threadIdx.x;
  int w = t >> 6, lane = t & 63;
  int l15 = lane & 15;
  int rowBase = blockIdx.x * 64;
  int r2 = t >> 2, p = t & 3;

  #pragma unroll
  for (int s = 0; s < 8; s++){
    int grow = rowBase + r2;
    u2 v = { 0u, 0u };
    if (grow < n) v = *(const u2*)(Hs + (size_t)s * NN * 8 + (size_t)grow * 8 + p * 2);
    *(u2*)(ldsA + r2 * 256 + ((s * 32 + p * 8) ^ ((r2 & 7) << 4))) = v;
  }
  #pragma unroll
  for (int iter = 0; iter < 3; iter++){
    int c = t / 16 + iter * 16;
    int kc = (t % 16) * 8;
    bh8 v = *(const bh8*)(W1t + (size_t)c * HD + kc);
    *(bh8*)(ldsW + c * 256 + ((kc * 2) ^ ((c & 7) << 4))) = v;
  }
  __syncthreads();

  f4 acc[3];
  #pragma unroll
  for (int i = 0; i < 3; i++) acc[i] = (f4)0.f;
  int rowf = (w << 4) + l15;
  #pragma unroll
  for (int ks = 0; ks < 4; ks++){
    bh8 fa = *(const bh8*)(ldsA + rowf * 256 + ((ks * 64 + (lane >> 4) * 16) ^ ((rowf & 7) << 4)));
    #pragma unroll
    for (int ct = 0; ct < 3; ct++){
      int colf = (ct << 4) + l15;
      bh8 fb = *(const bh8*)(ldsW + colf * 256 + ((ks * 64 + (lane >> 4) * 16) ^ ((colf & 7) << 4)));
      acc[ct] = __builtin_amdgcn_mfma_f32_16x16x32_bf16(fa, fb, acc[ct], 0, 0, 0);
    }
  }

  float bias0 = b1[l15];
  float bias1 = b1[16 + l15];
  bool v2ok = (l15 < 8);
  float bias2 = v2ok ? b1[32 + l15] : 0.f;

  #pragma unroll
  for (int i = 0; i < 4; i++){
    int r = rowBase + (w << 4) + ((lane >> 4) << 2) + i;
    float v0 = acc[0][i] + bias0;
    float v1 = acc[1][i] + bias1;
    float v2 = v2ok ? (acc[2][i] + bias2) : -1e30f;
    float m = fmaxf(fmaxf(v0, v1), v2);
    #pragma unroll
    for (int off = 1; off < 16; off <<= 1) m = fmaxf(m, __shfl_xor(m, off));
    float e0 = __expf(v0 - m), e1 = __expf(v1 - m);
    float e2 = v2ok ? __expf(v2 - m) : 0.f;
    float s = e0 + e1 + e2;
    #pragma unroll
    for (int off = 1; off < 16; off <<= 1) s += __shfl_xor(s, off);
    float ls = m + __logf(s);
    if (r < n){
      out[(size_t)r * NC + l15] = v0 - ls;
      out[(size_t)r * NC + 16 + l15] = v1 - ls;
      if (v2ok) out[(size_t)r * NC + 32 + l15] = v2 - ls;
    }
  }
}

extern "C" void kernel_launch(void* const* d_in, const int* in_sizes, int n_in,
                              void* d_out, int out_size, void* d_ws, size_t ws_size,
                              hipStream_t stream){
  const float* x  = (const float*)d_in[0];
  const int*   ei = (const int*)d_in[1];
  const float* ew = (const float*)d_in[2];
  const float* W0 = (const float*)d_in[3];
  const float* b0 = (const float*)d_in[4];
  const float* cW = (const float*)d_in[5];
  const float* W1 = (const float*)d_in[6];
  const float* b1 = (const float*)d_in[7];
  float* out = (float*)d_out;
  const int* src = ei;
  const int* dst = ei + NE;

  char* ws = (char*)d_ws;
  size_t off = 0;
  auto alloc = [&](size_t bytes) -> char* {
    char* p = ws + off;
    off += (bytes + 255) & ~(size_t)255;
    return p;
  };
  unsigned* x0b = (unsigned*)alloc((size_t)NN * 64 * 4);        // x0 sliced bf16x2
  unsigned* hbA = (unsigned*)alloc((size_t)NN * 64 * 4);        // h ping (sliced)
  unsigned* hbB = (unsigned*)alloc((size_t)NN * 64 * 4);        // h pong (sliced)
  unsigned* tb  = (unsigned*)alloc((size_t)NN * 64 * 4);        // T (sliced)
  unsigned short* wbuf = (unsigned short*)alloc(((size_t)FIN * HD + (size_t)NL * HD * HD + 48 * HD) * 2);
  unsigned short* W0t = wbuf;
  unsigned short* cWt = wbuf + (size_t)FIN * HD;
  unsigned short* W1t = cWt + (size_t)NL * HD * HD;
  int*   offs  = (int*)alloc((size_t)(NN + 1) * 4);
  int*   bcnt  = (int*)alloc(256 * 4);
  int*   gbase = (int*)alloc(257 * 4);
  int*   gcur  = (int*)alloc(256 * 4);
  u2*    tmp   = (u2*)alloc((size_t)NE * 8);
  u2*    epk   = (u2*)alloc((size_t)NE * 8);

  (void)hipMemsetAsync(bcnt, 0, 256 * 4, stream);
  hipLaunchKernelGGL(k_hist, dim3(P1B), dim3(256), 0, stream, dst, bcnt);
  hipLaunchKernelGGL(k_bscan, dim3(1), dim3(64), 0, stream, bcnt, gbase, gcur, offs);
  hipLaunchKernelGGL(k_part, dim3(P1B), dim3(256), 0, stream, src, dst, ew, gcur, tmp);
  hipLaunchKernelGGL(k_place, dim3(NBK), dim3(256), 0, stream, tmp, gbase, offs, epk);
  hipLaunchKernelGGL(k_twt_all, dim3(256), dim3(256), 0, stream, W0, cW, W1, wbuf);

  int gblocks = (NN + 63) / 64;
  hipLaunchKernelGGL(k_gemm0, dim3(gblocks), dim3(256), 0, stream, x, W0t, b0, x0b, hbA, NN);
  for (int l = 0; l < NL; l++){
    float beta = logf(0.5f / (float)(l + 1) + 1.0f);
    const unsigned* hin = (l & 1) ? hbB : hbA;
    unsigned* hout = (l & 1) ? hbA : hbB;
    hipLaunchKernelGGL(k_agg, dim3(NTILE * 8), dim3(256), 0, stream,
                       hin, x0b, offs, epk, tb, NN);
    hipLaunchKernelGGL(k_gemmL, dim3(gblocks), dim3(256), 0, stream,
                       tb, cWt + (size_t)l * HD * HD, beta, hout, NN);
  }
  hipLaunchKernelGGL(k_final, dim3(gblocks), dim3(256), 0, stream, hbA, W1t, b1, out, NN);
}

// Round 11
// 1031.325 us; speedup vs baseline: 1.5025x; 1.5025x over previous
//
#include <hip/hip_runtime.h>
#include <hip/hip_bf16.h>
#include <cmath>

#define NN 100000
#define NE 1600000
#define FIN 512
#define HD 128
#define NC 40
#define NL 8
#define NBK 196                      // ceil(NN / 512) buckets of 512 dsts
#define P1B 256                      // partition blocks
#define CHUNK ((NE + P1B - 1) / P1B) // edges per partition block

typedef __attribute__((ext_vector_type(8))) short bh8;
typedef __attribute__((ext_vector_type(4))) float f4;
typedef __attribute__((ext_vector_type(4))) unsigned int u4;
typedef __attribute__((ext_vector_type(2))) unsigned int u2;

__device__ __forceinline__ float bflo(unsigned p){ return __uint_as_float(p << 16); }
__device__ __forceinline__ float bfhi(unsigned p){ return __uint_as_float(p & 0xffff0000u); }
__device__ __forceinline__ unsigned short f2bf(float f){
  unsigned u = __float_as_uint(f);
  u += 0x7fffu + ((u >> 16) & 1u);
  return (unsigned short)(u >> 16);
}
__device__ __forceinline__ unsigned pack2(float a, float b){
  return (unsigned)f2bf(a) | ((unsigned)f2bf(b) << 16);
}

// ---------------- CSR build: radix partition by dst ----------------
__global__ __launch_bounds__(256) void k_hist(const int* __restrict__ dst,
                                              int* __restrict__ bcnt){
  __shared__ int h[256];
  int t = threadIdx.x;
  h[t] = 0;
  __syncthreads();
  int lo = blockIdx.x * CHUNK;
  int hi = lo + CHUNK < NE ? lo + CHUNK : NE;
  for (int i = lo + t; i < hi; i += 256)
    atomicAdd(&h[dst[i] >> 9], 1);
  __syncthreads();
  if (h[t]) atomicAdd(&bcnt[t], h[t]);
}

__global__ void k_bscan(const int* __restrict__ bcnt, int* __restrict__ gbase,
                        int* __restrict__ gcur, int* __restrict__ offs){
  int t = threadIdx.x;   // 64 threads
  int carry = 0;
  for (int base = 0; base < 256; base += 64){
    int v = bcnt[base + t];
    int orig = v;
    #pragma unroll
    for (int off = 1; off < 64; off <<= 1){
      int u = __shfl_up(v, off);
      if (t >= off) v += u;
    }
    int excl = carry + v - orig;
    gbase[base + t] = excl;
    gcur[base + t] = excl;
    carry += __shfl(v, 63);
  }
  if (t == 0){ gbase[256] = carry; offs[NN] = NE; }
}

__global__ __launch_bounds__(256) void k_part(const int* __restrict__ src,
                                              const int* __restrict__ dst,
                                              const float* __restrict__ w,
                                              int* __restrict__ gcur,
                                              u2* __restrict__ tmp){
  __shared__ int h[256];
  __shared__ int base[256];
  int t = threadIdx.x;
  h[t] = 0;
  __syncthreads();
  int lo = blockIdx.x * CHUNK;
  int hi = lo + CHUNK < NE ? lo + CHUNK : NE;
  for (int i = lo + t; i < hi; i += 256)
    atomicAdd(&h[dst[i] >> 9], 1);
  __syncthreads();
  int cnt = h[t];
  if (cnt) base[t] = atomicAdd(&gcur[t], cnt);
  h[t] = 0;
  __syncthreads();
  for (int i = lo + t; i < hi; i += 256){
    int d = dst[i];
    int bk = d >> 9;
    int r = atomicAdd(&h[bk], 1);
    u2 v = { (unsigned)src[i] | ((unsigned)(d & 511) << 17), __float_as_uint(w[i]) };
    tmp[base[bk] + r] = v;
  }
}

__global__ __launch_bounds__(256) void k_place(const u2* __restrict__ tmp,
                                               const int* __restrict__ gbase,
                                               int* __restrict__ offs,
                                               u2* __restrict__ epk){
  __shared__ int h[512];
  __shared__ int lofs[512];
  int b = blockIdx.x;
  int t = threadIdx.x;
  int e0 = gbase[b], e1 = gbase[b + 1];
  h[t] = 0; h[t + 256] = 0;
  __syncthreads();
  for (int i = e0 + t; i < e1; i += 256)
    atomicAdd(&h[tmp[i].x >> 17], 1);
  __syncthreads();
  if (t < 64){
    int carry = 0;
    for (int base = 0; base < 512; base += 64){
      int v = h[base + t];
      int orig = v;
      #pragma unroll
      for (int off = 1; off < 64; off <<= 1){
        int u = __shfl_up(v, off);
        if (t >= off) v += u;
      }
      lofs[base + t] = carry + v - orig;
      carry += __shfl(v, 63);
    }
  }
  __syncthreads();
  int d = b * 512 + t;
  if (d < NN) offs[d] = e0 + lofs[t];
  int d2 = b * 512 + 256 + t;
  if (d2 < NN) offs[d2] = e0 + lofs[256 + t];
  h[t] = 0; h[t + 256] = 0;
  __syncthreads();
  for (int i = e0 + t; i < e1; i += 256){
    u2 v = tmp[i];
    int d9 = v.x >> 17;
    int r = atomicAdd(&h[d9], 1);
    u2 o = { v.x & 0x1FFFFu, v.y };
    epk[e0 + lofs[d9] + r] = o;
  }
}

// ---------------- all weight transposes in one kernel ----------------
__global__ void k_twt_all(const float* __restrict__ W0, const float* __restrict__ cW,
                          const float* __restrict__ W1, unsigned short* __restrict__ out){
  const int n0 = FIN * HD;
  const int n1 = NL * HD * HD;
  const int total = n0 + n1 + 48 * HD;
  for (int i = blockIdx.x * blockDim.x + threadIdx.x; i < total; i += gridDim.x * blockDim.x){
    float v;
    if (i < n0){
      int c = i / FIN, k = i % FIN;
      v = W0[(size_t)k * HD + c];
    } else if (i < n0 + n1){
      int j = i - n0;
      int l = j / (HD * HD), r = j % (HD * HD);
      int c = r / HD, k = r % HD;
      v = cW[(size_t)l * HD * HD + k * HD + c];
    } else {
      int j = i - n0 - n1;
      int c = j / HD, k = j % HD;
      v = (c < NC) ? W1[(size_t)k * NC + c] : 0.f;
    }
    out[i] = f2bf(v);
  }
}

// ---------------- GEMM0: h0 = relu(x @ W0 + b0), write bf16 to two buffers ----------------
__global__ __launch_bounds__(256) void k_gemm0(const float* __restrict__ X,
                                               const unsigned short* __restrict__ Wt,
                                               const float* __restrict__ b0,
                                               unsigned* __restrict__ Ha,
                                               unsigned* __restrict__ Hb, int n){
  __shared__ __attribute__((aligned(16))) char lds[33792];
  char* ldsA = lds;           // 64 rows x 64 k bf16 (row stride 128 B)
  char* ldsW = lds + 8192;    // 128 c x 64 k bf16
  float* ldsO = (float*)lds;  // 64 x 132 f32 (reuse)
  int t = threadIdx.x;
  int w = t >> 6, lane = t & 63;
  int rowBase = blockIdx.x * 64;
  f4 acc[8];
  #pragma unroll
  for (int i = 0; i < 8; i++) acc[i] = (f4)0.f;

  for (int kk = 0; kk < 8; kk++){
    #pragma unroll
    for (int iter = 0; iter < 2; iter++){
      int r = t / 8 + iter * 32;
      int kc = (t % 8) * 8;
      int grow = rowBase + r;
      float4 f0 = {0,0,0,0}, f1 = {0,0,0,0};
      if (grow < n){
        const float4* p = (const float4*)(X + (size_t)grow * FIN + kk * 64 + kc);
        f0 = p[0]; f1 = p[1];
      }
      u4 pv = { pack2(f0.x, f0.y), pack2(f0.z, f0.w), pack2(f1.x, f1.y), pack2(f1.z, f1.w) };
      *(u4*)(ldsA + r * 128 + ((kc * 2) ^ ((r & 7) << 4))) = pv;
    }
    #pragma unroll
    for (int iter = 0; iter < 4; iter++){
      int c = t / 8 + iter * 32;
      int kc = (t % 8) * 8;
      bh8 v = *(const bh8*)(Wt + (size_t)c * FIN + kk * 64 + kc);
      *(bh8*)(ldsW + c * 128 + ((kc * 2) ^ ((c & 7) << 4))) = v;
    }
    __syncthreads();
    int rowf = (w << 4) + (lane & 15);
    #pragma unroll
    for (int ks = 0; ks < 2; ks++){
      bh8 fa = *(const bh8*)(ldsA + rowf * 128 + ((ks * 64 + (lane >> 4) * 16) ^ ((rowf & 7) << 4)));
      #pragma unroll
      for (int ct = 0; ct < 8; ct++){
        int colf = (ct << 4) + (lane & 15);
        bh8 fb = *(const bh8*)(ldsW + colf * 128 + ((ks * 64 + (lane >> 4) * 16) ^ ((colf & 7) << 4)));
        acc[ct] = __builtin_amdgcn_mfma_f32_16x16x32_bf16(fa, fb, acc[ct], 0, 0, 0);
      }
    }
    __syncthreads();
  }
  #pragma unroll
  for (int ct = 0; ct < 8; ct++){
    int colf = (ct << 4) + (lane & 15);
    float bb = b0[colf];
    #pragma unroll
    for (int i = 0; i < 4; i++){
      int r = (w << 4) + ((lane >> 4) << 2) + i;
      float v = acc[ct][i] + bb;
      ldsO[r * 132 + colf] = v > 0.f ? v : 0.f;
    }
  }
  __syncthreads();
  #pragma unroll
  for (int iter = 0; iter < 4; iter++){
    int r = iter * 16 + t / 16;
    int c8 = (t % 16) * 8;
    int grow = rowBase + r;
    if (grow < n){
      float* p = &ldsO[r * 132 + c8];
      u4 pv = { pack2(p[0], p[1]), pack2(p[2], p[3]), pack2(p[4], p[5]), pack2(p[6], p[7]) };
      *(u4*)(Ha + (size_t)grow * 64 + (t % 16) * 4) = pv;
      *(u4*)(Hb + (size_t)grow * 64 + (t % 16) * 4) = pv;
    }
  }
}

// ---------------- standalone aggregation: quad-owns-dst, full 256B rows, no LDS ----------------
// T[d] = bf16(0.9 * sum_e w_e * H[src_e] + 0.1 * X0[d])
__global__ __launch_bounds__(256) void k_agg(const unsigned* __restrict__ H,
                                             const unsigned* __restrict__ X0,
                                             const int* __restrict__ offs,
                                             const u2* __restrict__ epk,
                                             unsigned* __restrict__ T, int n){
  int t = threadIdx.x;
  int qid = (blockIdx.x << 4) + (t >> 4);   // global quad id
  int l16 = t & 15;
  int nq = gridDim.x << 4;
  for (int d = qid; d < n; d += nq){
    int e0 = offs[d], e1 = offs[d + 1];
    float a0=0.f,a1=0.f,a2=0.f,a3=0.f,a4=0.f,a5=0.f,a6=0.f,a7=0.f;
    int e = e0;
    for (; e + 7 < e1; e += 8){
      #pragma unroll
      for (int j = 0; j < 8; j++){
        u2 pe = epk[e + j];
        float wf = __uint_as_float(pe.y);
        u4 r = *(const u4*)(H + (size_t)pe.x * 64 + l16 * 4);
        a0 += wf * bflo(r.x); a1 += wf * bfhi(r.x);
        a2 += wf * bflo(r.y); a3 += wf * bfhi(r.y);
        a4 += wf * bflo(r.z); a5 += wf * bfhi(r.z);
        a6 += wf * bflo(r.w); a7 += wf * bfhi(r.w);
      }
    }
    for (; e < e1; e++){
      u2 pe = epk[e];
      float wf = __uint_as_float(pe.y);
      u4 r = *(const u4*)(H + (size_t)pe.x * 64 + l16 * 4);
      a0 += wf * bflo(r.x); a1 += wf * bfhi(r.x);
      a2 += wf * bflo(r.y); a3 += wf * bfhi(r.y);
      a4 += wf * bflo(r.z); a5 += wf * bfhi(r.z);
      a6 += wf * bflo(r.w); a7 += wf * bfhi(r.w);
    }
    u4 xp = *(const u4*)(X0 + (size_t)d * 64 + l16 * 4);
    float v0 = 0.9f*a0 + 0.1f*bflo(xp.x), v1 = 0.9f*a1 + 0.1f*bfhi(xp.x);
    float v2 = 0.9f*a2 + 0.1f*bflo(xp.y), v3 = 0.9f*a3 + 0.1f*bfhi(xp.y);
    float v4 = 0.9f*a4 + 0.1f*bflo(xp.z), v5 = 0.9f*a5 + 0.1f*bfhi(xp.z);
    float v6 = 0.9f*a6 + 0.1f*bflo(xp.w), v7 = 0.9f*a7 + 0.1f*bfhi(xp.w);
    u4 ov = { pack2(v0,v1), pack2(v2,v3), pack2(v4,v5), pack2(v6,v7) };
    *(u4*)(T + (size_t)d * 64 + l16 * 4) = ov;
  }
}

// ---------------- layer GEMM: H = relu((1-beta)*T + beta*(T @ W)), W from global ----------------
__global__ __launch_bounds__(256) void k_gemmL(const unsigned short* __restrict__ A,
                                               const unsigned short* __restrict__ Wt,
                                               float beta,
                                               unsigned* __restrict__ Hout, int n){
  __shared__ __attribute__((aligned(16))) char ldsA[16384];  // 64 x 128 bf16, swizzled
  int t = threadIdx.x;
  int w = t >> 6, lane = t & 63;
  int q = lane >> 4, l16 = lane & 15;
  int rowBase = blockIdx.x * 64;

  // load A tile: wave w loads its OWN rows w*16..w*16+15 (no barrier needed before MFMA)
  #pragma unroll
  for (int it = 0; it < 4; it++){
    int lr = (w << 4) + (lane >> 2);
    int j = it * 4 + (lane & 3);          // 16B chunk index 0..15
    int grow = rowBase + lr;
    bh8 v = (bh8)(short)0;
    if (grow < n) v = *(const bh8*)(A + (size_t)grow * HD + j * 8);
    *(bh8*)(ldsA + lr * 256 + ((j * 16) ^ ((lr & 7) << 4))) = v;
  }

  f4 acc[8];
  #pragma unroll
  for (int i = 0; i < 8; i++) acc[i] = (f4)0.f;
  int rowf = (w << 4) + l16;
  #pragma unroll
  for (int ks = 0; ks < 4; ks++){
    bh8 fa = *(const bh8*)(ldsA + rowf * 256 + ((ks * 64 + q * 16) ^ ((rowf & 7) << 4)));
    #pragma unroll
    for (int ct = 0; ct < 8; ct++){
      int colf = (ct << 4) + l16;
      bh8 fb = *(const bh8*)(Wt + (size_t)colf * HD + ks * 32 + q * 8);
      acc[ct] = __builtin_amdgcn_mfma_f32_16x16x32_bf16(fa, fb, acc[ct], 0, 0, 0);
    }
  }

  // epilogue: identity-mix from own ldsA rows, relu, write bf16 back into own ldsA rows
  #pragma unroll
  for (int ct = 0; ct < 8; ct++){
    int colf = (ct << 4) + l16;
    #pragma unroll
    for (int i = 0; i < 4; i++){
      int r = (w << 4) + (q << 2) + i;
      char* addr = ldsA + r * 256 + ((colf * 2) ^ ((r & 7) << 4));
      unsigned short tv = *(const unsigned short*)addr;
      float tf = __uint_as_float(((unsigned)tv) << 16);
      float v = (1.f - beta) * tf + beta * acc[ct][i];
      *(unsigned short*)addr = f2bf(v > 0.f ? v : 0.f);
    }
  }
  __syncthreads();

  // coalesced bf16 store
  #pragma unroll
  for (int iter = 0; iter < 4; iter++){
    int r = iter * 16 + t / 16;
    int kc = (t % 16) * 8;
    int grow = rowBase + r;
    if (grow < n){
      bh8 v = *(const bh8*)(ldsA + r * 256 + ((kc * 2) ^ ((r & 7) << 4)));
      *(bh8*)((unsigned short*)Hout + (size_t)grow * HD + kc) = v;
    }
  }
}

// ---------------- head + log_softmax: MFMA 64x48 tile, in-register softmax ----------------
__global__ __launch_bounds__(256) void k_final(const unsigned* __restrict__ H,
                                               const unsigned short* __restrict__ W1t, // [48][128]
                                               const float* __restrict__ b1,
                                               float* __restrict__ out, int n){
  __shared__ __attribute__((aligned(16))) char lds[16384 + 12288];
  char* ldsA = lds;            // 64 x 128 bf16, swizzled
  char* ldsW = lds + 16384;    // 48 x 128 bf16
  int t = threadIdx.x;
  int w = t >> 6, lane = t & 63;
  int l15 = lane & 15;
  int rowBase = blockIdx.x * 64;
  const unsigned short* Hs = (const unsigned short*)H;

  #pragma unroll
  for (int iter = 0; iter < 4; iter++){
    int r = t / 16 + iter * 16;
    int kc = (t % 16) * 8;
    int grow = rowBase + r;
    bh8 v = (bh8)(short)0;
    if (grow < n) v = *(const bh8*)(Hs + (size_t)grow * HD + kc);
    *(bh8*)(ldsA + r * 256 + ((kc * 2) ^ ((r & 7) << 4))) = v;
  }
  #pragma unroll
  for (int iter = 0; iter < 3; iter++){
    int c = t / 16 + iter * 16;
    int kc = (t % 16) * 8;
    bh8 v = *(const bh8*)(W1t + (size_t)c * HD + kc);
    *(bh8*)(ldsW + c * 256 + ((kc * 2) ^ ((c & 7) << 4))) = v;
  }
  __syncthreads();

  f4 acc[3];
  #pragma unroll
  for (int i = 0; i < 3; i++) acc[i] = (f4)0.f;
  int rowf = (w << 4) + l15;
  #pragma unroll
  for (int ks = 0; ks < 4; ks++){
    bh8 fa = *(const bh8*)(ldsA + rowf * 256 + ((ks * 64 + (lane >> 4) * 16) ^ ((rowf & 7) << 4)));
    #pragma unroll
    for (int ct = 0; ct < 3; ct++){
      int colf = (ct << 4) + l15;
      bh8 fb = *(const bh8*)(ldsW + colf * 256 + ((ks * 64 + (lane >> 4) * 16) ^ ((colf & 7) << 4)));
      acc[ct] = __builtin_amdgcn_mfma_f32_16x16x32_bf16(fa, fb, acc[ct], 0, 0, 0);
    }
  }

  float bias0 = b1[l15];
  float bias1 = b1[16 + l15];
  bool v2ok = (l15 < 8);
  float bias2 = v2ok ? b1[32 + l15] : 0.f;

  #pragma unroll
  for (int i = 0; i < 4; i++){
    int r = rowBase + (w << 4) + ((lane >> 4) << 2) + i;
    float v0 = acc[0][i] + bias0;
    float v1 = acc[1][i] + bias1;
    float v2 = v2ok ? (acc[2][i] + bias2) : -1e30f;
    float m = fmaxf(fmaxf(v0, v1), v2);
    #pragma unroll
    for (int off = 1; off < 16; off <<= 1) m = fmaxf(m, __shfl_xor(m, off));
    float e0 = __expf(v0 - m), e1 = __expf(v1 - m);
    float e2 = v2ok ? __expf(v2 - m) : 0.f;
    float s = e0 + e1 + e2;
    #pragma unroll
    for (int off = 1; off < 16; off <<= 1) s += __shfl_xor(s, off);
    float ls = m + __logf(s);
    if (r < n){
      out[(size_t)r * NC + l15] = v0 - ls;
      out[(size_t)r * NC + 16 + l15] = v1 - ls;
      if (v2ok) out[(size_t)r * NC + 32 + l15] = v2 - ls;
    }
  }
}

extern "C" void kernel_launch(void* const* d_in, const int* in_sizes, int n_in,
                              void* d_out, int out_size, void* d_ws, size_t ws_size,
                              hipStream_t stream){
  const float* x  = (const float*)d_in[0];
  const int*   ei = (const int*)d_in[1];
  const float* ew = (const float*)d_in[2];
  const float* W0 = (const float*)d_in[3];
  const float* b0 = (const float*)d_in[4];
  const float* cW = (const float*)d_in[5];
  const float* W1 = (const float*)d_in[6];
  const float* b1 = (const float*)d_in[7];
  float* out = (float*)d_out;
  const int* src = ei;
  const int* dst = ei + NE;

  char* ws = (char*)d_ws;
  size_t off = 0;
  auto alloc = [&](size_t bytes) -> char* {
    char* p = ws + off;
    off += (bytes + 255) & ~(size_t)255;
    return p;
  };
  unsigned* x0b = (unsigned*)alloc((size_t)NN * 64 * 4);        // x0 bf16x2
  unsigned* hbA = (unsigned*)alloc((size_t)NN * 64 * 4);        // h ping
  unsigned* hbB = (unsigned*)alloc((size_t)NN * 64 * 4);        // h pong
  unsigned* tb  = (unsigned*)alloc((size_t)NN * 64 * 4);        // T
  unsigned short* wbuf = (unsigned short*)alloc(((size_t)FIN * HD + (size_t)NL * HD * HD + 48 * HD) * 2);
  unsigned short* W0t = wbuf;
  unsigned short* cWt = wbuf + (size_t)FIN * HD;
  unsigned short* W1t = cWt + (size_t)NL * HD * HD;
  int*   offs  = (int*)alloc((size_t)(NN + 1) * 4);
  int*   bcnt  = (int*)alloc(256 * 4);
  int*   gbase = (int*)alloc(257 * 4);
  int*   gcur  = (int*)alloc(256 * 4);
  u2*    tmp   = (u2*)alloc((size_t)NE * 8);
  u2*    epk   = (u2*)alloc((size_t)NE * 8);

  (void)hipMemsetAsync(bcnt, 0, 256 * 4, stream);
  hipLaunchKernelGGL(k_hist, dim3(P1B), dim3(256), 0, stream, dst, bcnt);
  hipLaunchKernelGGL(k_bscan, dim3(1), dim3(64), 0, stream, bcnt, gbase, gcur, offs);
  hipLaunchKernelGGL(k_part, dim3(P1B), dim3(256), 0, stream, src, dst, ew, gcur, tmp);
  hipLaunchKernelGGL(k_place, dim3(NBK), dim3(256), 0, stream, tmp, gbase, offs, epk);
  hipLaunchKernelGGL(k_twt_all, dim3(256), dim3(256), 0, stream, W0, cW, W1, wbuf);

  int gblocks = (NN + 63) / 64;
  hipLaunchKernelGGL(k_gemm0, dim3(gblocks), dim3(256), 0, stream, x, W0t, b0, x0b, hbA, NN);
  for (int l = 0; l < NL; l++){
    float beta = logf(0.5f / (float)(l + 1) + 1.0f);
    const unsigned* hin = (l & 1) ? hbB : hbA;
    unsigned* hout = (l & 1) ? hbA : hbB;
    hipLaunchKernelGGL(k_agg, dim3(2048), dim3(256), 0, stream,
                       hin, x0b, offs, epk, tb, NN);
    hipLaunchKernelGGL(k_gemmL, dim3(gblocks), dim3(256), 0, stream,
                       (const unsigned short*)tb, cWt + (size_t)l * HD * HD, beta, hout, NN);
  }
  hipLaunchKernelGGL(k_final, dim3(gblocks), dim3(256), 0, stream, hbA, W1t, b1, out, NN);
}

// Round 12
// 990.959 us; speedup vs baseline: 1.5637x; 1.0407x over previous
//
#include <hip/hip_runtime.h>
#include <hip/hip_bf16.h>
#include <cmath>

#define NN 100000
#define NE 1600000
#define FIN 512
#define HD 128
#define NC 40
#define NL 8
#define NBK 196                      // ceil(NN / 512) buckets of 512 dsts
#define P1B 256                      // partition blocks
#define CHUNK ((NE + P1B - 1) / P1B) // edges per partition block

typedef __attribute__((ext_vector_type(8))) short bh8;
typedef __attribute__((ext_vector_type(4))) float f4;
typedef __attribute__((ext_vector_type(4))) unsigned int u4;
typedef __attribute__((ext_vector_type(2))) unsigned int u2;

__device__ __forceinline__ float bflo(unsigned p){ return __uint_as_float(p << 16); }
__device__ __forceinline__ float bfhi(unsigned p){ return __uint_as_float(p & 0xffff0000u); }
__device__ __forceinline__ unsigned short f2bf(float f){
  unsigned u = __float_as_uint(f);
  u += 0x7fffu + ((u >> 16) & 1u);
  return (unsigned short)(u >> 16);
}
__device__ __forceinline__ unsigned pack2(float a, float b){
  return (unsigned)f2bf(a) | ((unsigned)f2bf(b) << 16);
}

// ---------------- CSR build: radix partition by dst ----------------
__global__ __launch_bounds__(256) void k_hist(const int* __restrict__ dst,
                                              int* __restrict__ bcnt){
  __shared__ int h[256];
  int t = threadIdx.x;
  h[t] = 0;
  __syncthreads();
  int lo = blockIdx.x * CHUNK;
  int hi = lo + CHUNK < NE ? lo + CHUNK : NE;
  for (int i = lo + t; i < hi; i += 256)
    atomicAdd(&h[dst[i] >> 9], 1);
  __syncthreads();
  if (h[t]) atomicAdd(&bcnt[t], h[t]);
}

__global__ void k_bscan(const int* __restrict__ bcnt, int* __restrict__ gbase,
                        int* __restrict__ gcur, int* __restrict__ offs){
  int t = threadIdx.x;   // 64 threads
  int carry = 0;
  for (int base = 0; base < 256; base += 64){
    int v = bcnt[base + t];
    int orig = v;
    #pragma unroll
    for (int off = 1; off < 64; off <<= 1){
      int u = __shfl_up(v, off);
      if (t >= off) v += u;
    }
    int excl = carry + v - orig;
    gbase[base + t] = excl;
    gcur[base + t] = excl;
    carry += __shfl(v, 63);
  }
  if (t == 0){ gbase[256] = carry; offs[NN] = NE; }
}

__global__ __launch_bounds__(256) void k_part(const int* __restrict__ src,
                                              const int* __restrict__ dst,
                                              const float* __restrict__ w,
                                              int* __restrict__ gcur,
                                              u2* __restrict__ tmp){
  __shared__ int h[256];
  __shared__ int base[256];
  int t = threadIdx.x;
  h[t] = 0;
  __syncthreads();
  int lo = blockIdx.x * CHUNK;
  int hi = lo + CHUNK < NE ? lo + CHUNK : NE;
  for (int i = lo + t; i < hi; i += 256)
    atomicAdd(&h[dst[i] >> 9], 1);
  __syncthreads();
  int cnt = h[t];
  if (cnt) base[t] = atomicAdd(&gcur[t], cnt);
  h[t] = 0;
  __syncthreads();
  for (int i = lo + t; i < hi; i += 256){
    int d = dst[i];
    int bk = d >> 9;
    int r = atomicAdd(&h[bk], 1);
    u2 v = { (unsigned)src[i] | ((unsigned)(d & 511) << 17), __float_as_uint(w[i]) };
    tmp[base[bk] + r] = v;
  }
}

__global__ __launch_bounds__(256) void k_place(const u2* __restrict__ tmp,
                                               const int* __restrict__ gbase,
                                               int* __restrict__ offs,
                                               u2* __restrict__ epk){
  __shared__ int h[512];
  __shared__ int lofs[512];
  int b = blockIdx.x;
  int t = threadIdx.x;
  int e0 = gbase[b], e1 = gbase[b + 1];
  h[t] = 0; h[t + 256] = 0;
  __syncthreads();
  for (int i = e0 + t; i < e1; i += 256)
    atomicAdd(&h[tmp[i].x >> 17], 1);
  __syncthreads();
  if (t < 64){
    int carry = 0;
    for (int base = 0; base < 512; base += 64){
      int v = h[base + t];
      int orig = v;
      #pragma unroll
      for (int off = 1; off < 64; off <<= 1){
        int u = __shfl_up(v, off);
        if (t >= off) v += u;
      }
      lofs[base + t] = carry + v - orig;
      carry += __shfl(v, 63);
    }
  }
  __syncthreads();
  int d = b * 512 + t;
  if (d < NN) offs[d] = e0 + lofs[t];
  int d2 = b * 512 + 256 + t;
  if (d2 < NN) offs[d2] = e0 + lofs[256 + t];
  h[t] = 0; h[t + 256] = 0;
  __syncthreads();
  for (int i = e0 + t; i < e1; i += 256){
    u2 v = tmp[i];
    int d9 = v.x >> 17;
    int r = atomicAdd(&h[d9], 1);
    u2 o = { v.x & 0x1FFFFu, v.y };
    epk[e0 + lofs[d9] + r] = o;
  }
}

// ---------------- all weight transposes in one kernel ----------------
__global__ void k_twt_all(const float* __restrict__ W0, const float* __restrict__ cW,
                          const float* __restrict__ W1, unsigned short* __restrict__ out){
  const int n0 = FIN * HD;
  const int n1 = NL * HD * HD;
  const int total = n0 + n1 + 48 * HD;
  for (int i = blockIdx.x * blockDim.x + threadIdx.x; i < total; i += gridDim.x * blockDim.x){
    float v;
    if (i < n0){
      int c = i / FIN, k = i % FIN;
      v = W0[(size_t)k * HD + c];
    } else if (i < n0 + n1){
      int j = i - n0;
      int l = j / (HD * HD), r = j % (HD * HD);
      int c = r / HD, k = r % HD;
      v = cW[(size_t)l * HD * HD + k * HD + c];
    } else {
      int j = i - n0 - n1;
      int c = j / HD, k = j % HD;
      v = (c < NC) ? W1[(size_t)k * NC + c] : 0.f;
    }
    out[i] = f2bf(v);
  }
}

// ---------------- GEMM0: h0 = relu(x @ W0 + b0), write bf16 to two buffers ----------------
__global__ __launch_bounds__(256) void k_gemm0(const float* __restrict__ X,
                                               const unsigned short* __restrict__ Wt,
                                               const float* __restrict__ b0,
                                               unsigned* __restrict__ Ha,
                                               unsigned* __restrict__ Hb, int n){
  __shared__ __attribute__((aligned(16))) char lds[33792];
  char* ldsA = lds;           // 64 rows x 64 k bf16 (row stride 128 B)
  char* ldsW = lds + 8192;    // 128 c x 64 k bf16
  float* ldsO = (float*)lds;  // 64 x 132 f32 (reuse)
  int t = threadIdx.x;
  int w = t >> 6, lane = t & 63;
  int rowBase = blockIdx.x * 64;
  f4 acc[8];
  #pragma unroll
  for (int i = 0; i < 8; i++) acc[i] = (f4)0.f;

  for (int kk = 0; kk < 8; kk++){
    #pragma unroll
    for (int iter = 0; iter < 2; iter++){
      int r = t / 8 + iter * 32;
      int kc = (t % 8) * 8;
      int grow = rowBase + r;
      float4 f0 = {0,0,0,0}, f1 = {0,0,0,0};
      if (grow < n){
        const float4* p = (const float4*)(X + (size_t)grow * FIN + kk * 64 + kc);
        f0 = p[0]; f1 = p[1];
      }
      u4 pv = { pack2(f0.x, f0.y), pack2(f0.z, f0.w), pack2(f1.x, f1.y), pack2(f1.z, f1.w) };
      *(u4*)(ldsA + r * 128 + ((kc * 2) ^ ((r & 7) << 4))) = pv;
    }
    #pragma unroll
    for (int iter = 0; iter < 4; iter++){
      int c = t / 8 + iter * 32;
      int kc = (t % 8) * 8;
      bh8 v = *(const bh8*)(Wt + (size_t)c * FIN + kk * 64 + kc);
      *(bh8*)(ldsW + c * 128 + ((kc * 2) ^ ((c & 7) << 4))) = v;
    }
    __syncthreads();
    int rowf = (w << 4) + (lane & 15);
    #pragma unroll
    for (int ks = 0; ks < 2; ks++){
      bh8 fa = *(const bh8*)(ldsA + rowf * 128 + ((ks * 64 + (lane >> 4) * 16) ^ ((rowf & 7) << 4)));
      #pragma unroll
      for (int ct = 0; ct < 8; ct++){
        int colf = (ct << 4) + (lane & 15);
        bh8 fb = *(const bh8*)(ldsW + colf * 128 + ((ks * 64 + (lane >> 4) * 16) ^ ((colf & 7) << 4)));
        acc[ct] = __builtin_amdgcn_mfma_f32_16x16x32_bf16(fa, fb, acc[ct], 0, 0, 0);
      }
    }
    __syncthreads();
  }
  #pragma unroll
  for (int ct = 0; ct < 8; ct++){
    int colf = (ct << 4) + (lane & 15);
    float bb = b0[colf];
    #pragma unroll
    for (int i = 0; i < 4; i++){
      int r = (w << 4) + ((lane >> 4) << 2) + i;
      float v = acc[ct][i] + bb;
      ldsO[r * 132 + colf] = v > 0.f ? v : 0.f;
    }
  }
  __syncthreads();
  #pragma unroll
  for (int iter = 0; iter < 4; iter++){
    int r = iter * 16 + t / 16;
    int c8 = (t % 16) * 8;
    int grow = rowBase + r;
    if (grow < n){
      float* p = &ldsO[r * 132 + c8];
      u4 pv = { pack2(p[0], p[1]), pack2(p[2], p[3]), pack2(p[4], p[5]), pack2(p[6], p[7]) };
      *(u4*)(Ha + (size_t)grow * 64 + (t % 16) * 4) = pv;
      *(u4*)(Hb + (size_t)grow * 64 + (t % 16) * 4) = pv;
    }
  }
}

// ---------------- fused layer: 8 waves, quad owns 2 rows, masked 8-wide gather ----------------
// Hout = relu((1-beta)*T + beta*(T @ W)),  T = 0.9*(A h) + 0.1*x0
// last!=0: also compute logits = H @ W1 + b1 and out = log_softmax(logits); skip Hout store.
__global__ __launch_bounds__(512) void k_layer(const unsigned* __restrict__ Hin,
                                               const unsigned* __restrict__ X0,
                                               const int* __restrict__ offs,
                                               const u2* __restrict__ epk,
                                               const unsigned short* __restrict__ Wt,
                                               float beta,
                                               unsigned* __restrict__ Hout, int n,
                                               const unsigned short* __restrict__ W1t,
                                               const float* __restrict__ b1,
                                               float* __restrict__ out, int last){
  __shared__ __attribute__((aligned(16))) char ldsA[16384];  // 64 x 128 bf16, stride 256 B, swizzled
  int t = threadIdx.x;
  int w = t >> 6, lane = t & 63;
  int q = lane >> 4, l16 = lane & 15;
  int quadId = (w << 2) + q;           // 0..31
  int rowBase = blockIdx.x * 64;

  // gather: quad quadId owns rows quadId*2 + rr; all 16 lanes read the SAME edge
  // record (quad-uniform -> HW broadcast), each lane gathers its 16B row slice.
  // Masked 8-wide loop: tail edges processed in the same unrolled iteration
  // (dummy edges gather row 0 with weight 0 -> contribute nothing, L1-hot).
  #pragma unroll
  for (int rr = 0; rr < 2; rr++){
    int lr = (quadId << 1) + rr;
    int d = rowBase + lr;
    bool act = d < n;
    int e0 = act ? offs[d] : 0;
    int e1 = act ? offs[d + 1] : 0;
    float a0=0.f,a1=0.f,a2=0.f,a3=0.f,a4=0.f,a5=0.f,a6=0.f,a7=0.f;
    for (int e = e0; e < e1; e += 8){
      #pragma unroll
      for (int j = 0; j < 8; j++){
        int ee = e + j;
        u2 pe = { 0u, 0u };
        if (ee < e1) pe = epk[ee];
        float wf = __uint_as_float(pe.y);
        u4 r = *(const u4*)(Hin + (size_t)pe.x * 64 + l16 * 4);
        a0 += wf * bflo(r.x); a1 += wf * bfhi(r.x);
        a2 += wf * bflo(r.y); a3 += wf * bfhi(r.y);
        a4 += wf * bflo(r.z); a5 += wf * bfhi(r.z);
        a6 += wf * bflo(r.w); a7 += wf * bfhi(r.w);
      }
    }
    u4 ov = { 0u, 0u, 0u, 0u };
    if (act){
      u4 xp = *(const u4*)(X0 + (size_t)d * 64 + l16 * 4);
      float v0 = 0.9f*a0 + 0.1f*bflo(xp.x), v1 = 0.9f*a1 + 0.1f*bfhi(xp.x);
      float v2 = 0.9f*a2 + 0.1f*bflo(xp.y), v3 = 0.9f*a3 + 0.1f*bfhi(xp.y);
      float v4 = 0.9f*a4 + 0.1f*bflo(xp.z), v5 = 0.9f*a5 + 0.1f*bfhi(xp.z);
      float v6 = 0.9f*a6 + 0.1f*bflo(xp.w), v7 = 0.9f*a7 + 0.1f*bfhi(xp.w);
      ov = (u4){ pack2(v0,v1), pack2(v2,v3), pack2(v4,v5), pack2(v6,v7) };
    }
    *(u4*)(ldsA + lr * 256 + ((l16 * 16) ^ ((lr & 7) << 4))) = ov;
  }
  __syncthreads();   // A-rows cross waves

  // MFMA: wave w computes rows (w&3)*16..+16, cols (w>>2)*64..+64
  f4 acc[4];
  #pragma unroll
  for (int i = 0; i < 4; i++) acc[i] = (f4)0.f;
  int rowf = ((w & 3) << 4) + l16;
  int colBase = (w >> 2) << 6;
  #pragma unroll
  for (int ks = 0; ks < 4; ks++){
    bh8 fa = *(const bh8*)(ldsA + rowf * 256 + ((ks * 64 + q * 16) ^ ((rowf & 7) << 4)));
    #pragma unroll
    for (int ct = 0; ct < 4; ct++){
      int colf = colBase + (ct << 4) + l16;
      bh8 fb = *(const bh8*)(Wt + (size_t)colf * HD + ks * 32 + q * 8);
      acc[ct] = __builtin_amdgcn_mfma_f32_16x16x32_bf16(fa, fb, acc[ct], 0, 0, 0);
    }
  }

  // epilogue: identity-mix (T re-read from ldsA at same (r,c)), relu, write back bf16
  #pragma unroll
  for (int ct = 0; ct < 4; ct++){
    int colf = colBase + (ct << 4) + l16;
    #pragma unroll
    for (int i = 0; i < 4; i++){
      int r = ((w & 3) << 4) + (q << 2) + i;
      char* addr = ldsA + r * 256 + ((colf * 2) ^ ((r & 7) << 4));
      unsigned short tv = *(const unsigned short*)addr;
      float tf = __uint_as_float(((unsigned)tv) << 16);
      float v = (1.f - beta) * tf + beta * acc[ct][i];
      *(unsigned short*)addr = f2bf(v > 0.f ? v : 0.f);
    }
  }
  __syncthreads();

  if (!last){
    // coalesced bf16 store: 64 rows x 16 chunks of 16B = 1024 chunks / 512 threads
    #pragma unroll
    for (int iter = 0; iter < 2; iter++){
      int r = iter * 32 + t / 16;
      int kc = (t % 16) * 8;
      int grow = rowBase + r;
      if (grow < n){
        bh8 v = *(const bh8*)(ldsA + r * 256 + ((kc * 2) ^ ((r & 7) << 4)));
        *(bh8*)((unsigned short*)Hout + (size_t)grow * HD + kc) = v;
      }
    }
  } else if (w < 4){
    // fused head + log_softmax: waves 0-3, rows w*16..w*16+15, W1 frags from global
    int l15 = lane & 15;
    f4 hacc[3];
    #pragma unroll
    for (int i = 0; i < 3; i++) hacc[i] = (f4)0.f;
    int hrow = (w << 4) + l15;
    #pragma unroll
    for (int ks = 0; ks < 4; ks++){
      bh8 fa = *(const bh8*)(ldsA + hrow * 256 + ((ks * 64 + (lane >> 4) * 16) ^ ((hrow & 7) << 4)));
      #pragma unroll
      for (int ct = 0; ct < 3; ct++){
        int colf = (ct << 4) + l15;
        bh8 fb = *(const bh8*)(W1t + (size_t)colf * HD + ks * 32 + (lane >> 4) * 8);
        hacc[ct] = __builtin_amdgcn_mfma_f32_16x16x32_bf16(fa, fb, hacc[ct], 0, 0, 0);
      }
    }
    float bias0 = b1[l15];
    float bias1 = b1[16 + l15];
    bool v2ok = (l15 < 8);
    float bias2 = v2ok ? b1[32 + l15] : 0.f;
    #pragma unroll
    for (int i = 0; i < 4; i++){
      int r = rowBase + (w << 4) + ((lane >> 4) << 2) + i;
      float v0 = hacc[0][i] + bias0;
      float v1 = hacc[1][i] + bias1;
      float v2 = v2ok ? (hacc[2][i] + bias2) : -1e30f;
      float m = fmaxf(fmaxf(v0, v1), v2);
      #pragma unroll
      for (int off = 1; off < 16; off <<= 1) m = fmaxf(m, __shfl_xor(m, off));
      float e0 = __expf(v0 - m), e1 = __expf(v1 - m);
      float e2 = v2ok ? __expf(v2 - m) : 0.f;
      float s = e0 + e1 + e2;
      #pragma unroll
      for (int off = 1; off < 16; off <<= 1) s += __shfl_xor(s, off);
      float ls = m + __logf(s);
      if (r < n){
        out[(size_t)r * NC + l15] = v0 - ls;
        out[(size_t)r * NC + 16 + l15] = v1 - ls;
        if (v2ok) out[(size_t)r * NC + 32 + l15] = v2 - ls;
      }
    }
  }
}

extern "C" void kernel_launch(void* const* d_in, const int* in_sizes, int n_in,
                              void* d_out, int out_size, void* d_ws, size_t ws_size,
                              hipStream_t stream){
  const float* x  = (const float*)d_in[0];
  const int*   ei = (const int*)d_in[1];
  const float* ew = (const float*)d_in[2];
  const float* W0 = (const float*)d_in[3];
  const float* b0 = (const float*)d_in[4];
  const float* cW = (const float*)d_in[5];
  const float* W1 = (const float*)d_in[6];
  const float* b1 = (const float*)d_in[7];
  float* out = (float*)d_out;
  const int* src = ei;
  const int* dst = ei + NE;

  char* ws = (char*)d_ws;
  size_t off = 0;
  auto alloc = [&](size_t bytes) -> char* {
    char* p = ws + off;
    off += (bytes + 255) & ~(size_t)255;
    return p;
  };
  unsigned* x0b = (unsigned*)alloc((size_t)NN * 64 * 4);        // x0 bf16x2
  unsigned* hbA = (unsigned*)alloc((size_t)NN * 64 * 4);        // h ping
  unsigned* hbB = (unsigned*)alloc((size_t)NN * 64 * 4);        // h pong
  unsigned short* wbuf = (unsigned short*)alloc(((size_t)FIN * HD + (size_t)NL * HD * HD + 48 * HD) * 2);
  unsigned short* W0t = wbuf;
  unsigned short* cWt = wbuf + (size_t)FIN * HD;
  unsigned short* W1t = cWt + (size_t)NL * HD * HD;
  int*   offs  = (int*)alloc((size_t)(NN + 1) * 4);
  int*   bcnt  = (int*)alloc(256 * 4);
  int*   gbase = (int*)alloc(257 * 4);
  int*   gcur  = (int*)alloc(256 * 4);
  u2*    tmp   = (u2*)alloc((size_t)NE * 8);
  u2*    epk   = (u2*)alloc((size_t)NE * 8);

  (void)hipMemsetAsync(bcnt, 0, 256 * 4, stream);
  hipLaunchKernelGGL(k_hist, dim3(P1B), dim3(256), 0, stream, dst, bcnt);
  hipLaunchKernelGGL(k_bscan, dim3(1), dim3(64), 0, stream, bcnt, gbase, gcur, offs);
  hipLaunchKernelGGL(k_part, dim3(P1B), dim3(256), 0, stream, src, dst, ew, gcur, tmp);
  hipLaunchKernelGGL(k_place, dim3(NBK), dim3(256), 0, stream, tmp, gbase, offs, epk);
  hipLaunchKernelGGL(k_twt_all, dim3(256), dim3(256), 0, stream, W0, cW, W1, wbuf);

  int gblocks = (NN + 63) / 64;
  hipLaunchKernelGGL(k_gemm0, dim3(gblocks), dim3(256), 0, stream, x, W0t, b0, x0b, hbA, NN);
  for (int l = 0; l < NL; l++){
    float beta = logf(0.5f / (float)(l + 1) + 1.0f);
    const unsigned* hin = (l & 1) ? hbB : hbA;
    unsigned* hout = (l & 1) ? hbA : hbB;
    hipLaunchKernelGGL(k_layer, dim3(gblocks), dim3(512), 0, stream,
                       hin, x0b, offs, epk, cWt + (size_t)l * HD * HD, beta, hout, NN,
                       W1t, b1, out, (l == NL - 1) ? 1 : 0);
  }
}